// Round 2
// baseline (770.235 us; speedup 1.0000x reference)
//
#include <hip/hip_runtime.h>
#include <math.h>

#define B_   256
#define S_   200
#define NQ_  400
#define K_   4
#define M_   50
#define KD_  50
#define VD_  200
#define FD_  50
#define T_   (B_*S_)   // 51200 tokens

// ---------------------------------------------------------------------------
// Kernel 1: per-token embeddings + correlation softmax. One wave (64 lanes)
// per token, 4 tokens per 256-thread block.
// Writes: V[T][VD] (value_emb), corr[T][M]
// ---------------------------------------------------------------------------
__global__ __launch_bounds__(256) void k1_embed(
    const int* __restrict__ q_data, const int* __restrict__ r_data,
    const float* __restrict__ q_tab, const float* __restrict__ key_mem,
    const float* __restrict__ W_qk, const float* __restrict__ b_qk,
    const float* __restrict__ W_v3, const float* __restrict__ b_v,
    float* __restrict__ V, float* __restrict__ corr)
{
    const int wave = threadIdx.x >> 6;
    const int lane = threadIdx.x & 63;
    const int tok  = blockIdx.x * 4 + wave;

    const int q = q_data[tok];
    const int r = r_data[tok];
    const float qmask = (q > 0) ? 1.0f : 0.0f;
    int idx = q - 1;
    if (idx < 0) idx = 0;
    if (idx > NQ_ - 1) idx = NQ_ - 1;

    float wc[K_];
#pragma unroll
    for (int k = 0; k < K_; ++k) {
        float dist = fabsf((float)k - (float)r) / (float)(K_ - 1);
        float w = 1.0f - dist;
        wc[k] = (w > 0.0f) ? w : 0.0f;
    }

    // value_emb = b_v + qmask * sum_k wc[k] * W_v3[k][idx][:]
    for (int j = lane; j < VD_; j += 64) {
        float s = 0.0f;
#pragma unroll
        for (int k = 0; k < K_; ++k)
            s += wc[k] * W_v3[((size_t)k * NQ_ + idx) * VD_ + j];
        V[(size_t)tok * VD_ + j] = b_v[j] + qmask * s;
    }

    // query_key = tanh(q_emb @ W_qk + b_qk); lanes 0..49
    __shared__ float sqk[4][KD_];
    const float* qe = q_tab + (size_t)q * KD_;
    if (lane < KD_) {
        float acc = b_qk[lane];
#pragma unroll 10
        for (int k = 0; k < KD_; ++k)
            acc += qe[k] * W_qk[k * KD_ + lane];
        sqk[wave][lane] = tanhf(acc);
    }
    __syncthreads();

    // corr = softmax(query_key @ key_mem^T) over M
    float c = -INFINITY;
    if (lane < M_) {
        float acc = 0.0f;
#pragma unroll 10
        for (int k = 0; k < KD_; ++k)
            acc += sqk[wave][k] * key_mem[lane * KD_ + k];
        c = acc;
    }
    float mx = c;
#pragma unroll
    for (int off = 32; off; off >>= 1) mx = fmaxf(mx, __shfl_xor(mx, off));
    float e = (lane < M_) ? expf(c - mx) : 0.0f;
    float sm = e;
#pragma unroll
    for (int off = 32; off; off >>= 1) sm += __shfl_xor(sm, off);
    if (lane < M_) corr[(size_t)tok * M_ + lane] = e / sm;
}

// ---------------------------------------------------------------------------
// Kernel 2: erase = sigmoid(V@W_e + b_e), add = tanh(V@W_a + b_a)
// Tiled f32 GEMM, 16 tokens/block, K-tiles of 25, both W tiles in LDS (40KB).
// Thread (ty,tx): token ty, column pairs c = 2*tx + 32*j (j<7, c<200).
// ---------------------------------------------------------------------------
#define BT  16
#define BK2 25
__global__ __launch_bounds__(256) void k2_gemm(
    const float* __restrict__ V,
    const float* __restrict__ W_e, const float* __restrict__ b_e,
    const float* __restrict__ W_a, const float* __restrict__ b_a,
    float* __restrict__ erase, float* __restrict__ add)
{
    __shared__ float sWe[BK2][VD_];
    __shared__ float sWa[BK2][VD_];
    __shared__ float sV[BT][BK2];

    const int tid = threadIdx.x;
    const int ty = tid >> 4;       // token 0..15
    const int tx = tid & 15;       // column lane
    const int tok0 = blockIdx.x * BT;
    const int tok = tok0 + ty;

    float2 accE[7], accA[7];
#pragma unroll
    for (int j = 0; j < 7; ++j) {
        accE[j] = make_float2(0.f, 0.f);
        accA[j] = make_float2(0.f, 0.f);
    }

    for (int kt = 0; kt < VD_; kt += BK2) {
        __syncthreads();
        // stage W_e/W_a tiles: 25x200 floats each, float4 loads
        for (int i = tid; i < (BK2 * VD_) / 4; i += 256) {
            int row = i / (VD_ / 4), c4 = (i % (VD_ / 4)) * 4;
            *(float4*)&sWe[row][c4] = *(const float4*)&W_e[(kt + row) * VD_ + c4];
            *(float4*)&sWa[row][c4] = *(const float4*)&W_a[(kt + row) * VD_ + c4];
        }
        for (int i = tid; i < BT * BK2; i += 256) {   // FIXED: was if(tid<400) with 256 threads
            int t = i / BK2, kk = i % BK2;
            sV[t][kk] = V[(size_t)(tok0 + t) * VD_ + kt + kk];
        }
        __syncthreads();

#pragma unroll 5
        for (int kk = 0; kk < BK2; ++kk) {
            float vr = sV[ty][kk];
#pragma unroll
            for (int j = 0; j < 7; ++j) {
                int c = 2 * tx + 32 * j;
                if (c < VD_) {
                    float2 we = *(const float2*)&sWe[kk][c];
                    float2 wa = *(const float2*)&sWa[kk][c];
                    accE[j].x += vr * we.x; accE[j].y += vr * we.y;
                    accA[j].x += vr * wa.x; accA[j].y += vr * wa.y;
                }
            }
        }
    }

#pragma unroll
    for (int j = 0; j < 7; ++j) {
        int c = 2 * tx + 32 * j;
        if (c < VD_) {
            float2 be = *(const float2*)&b_e[c];
            float2 ba = *(const float2*)&b_a[c];
            float2 eo, ao;
            eo.x = 1.0f / (1.0f + expf(-(accE[j].x + be.x)));
            eo.y = 1.0f / (1.0f + expf(-(accE[j].y + be.y)));
            ao.x = tanhf(accA[j].x + ba.x);
            ao.y = tanhf(accA[j].y + ba.y);
            *(float2*)&erase[(size_t)tok * VD_ + c] = eo;
            *(float2*)&add[(size_t)tok * VD_ + c]   = ao;
        }
    }
}

// ---------------------------------------------------------------------------
// Kernel 3: sequential memory scan. One block per batch. Thread j owns memory
// column j (j<200) entirely in registers (mem[50]); only the 50-wide corr row
// is shared via LDS per step.
// ---------------------------------------------------------------------------
__global__ __launch_bounds__(256) void k3_scan(
    const float* __restrict__ init_mem,
    const float* __restrict__ corr, const float* __restrict__ erase,
    const float* __restrict__ add, float* __restrict__ reads)
{
    const int b = blockIdx.x;
    const int j = threadIdx.x;
    const bool act = (j < VD_);

    float mem[M_];
    if (act) {
#pragma unroll
        for (int m = 0; m < M_; ++m) mem[m] = init_mem[m * VD_ + j];
    }

    __shared__ float wsh[M_];
    const float* cb = corr  + (size_t)b * S_ * M_;
    const float* eb = erase + (size_t)b * S_ * VD_;
    const float* ab = add   + (size_t)b * S_ * VD_;
    float* rb       = reads + (size_t)b * S_ * VD_;

    for (int s = 0; s < S_; ++s) {
        if (threadIdx.x < M_) wsh[threadIdx.x] = cb[s * M_ + threadIdx.x];
        float e = 0.f, a = 0.f;
        if (act) { e = eb[s * VD_ + j]; a = ab[s * VD_ + j]; }
        __syncthreads();
        float r0 = 0.f, r1 = 0.f;
#pragma unroll
        for (int m = 0; m < M_; m += 2) {
            float w0 = wsh[m], w1 = wsh[m + 1];
            r0 += w0 * mem[m];
            float t0 = 1.0f - w0 * e;
            mem[m] = mem[m] * t0 + w0 * a;
            r1 += w1 * mem[m + 1];
            float t1 = 1.0f - w1 * e;
            mem[m + 1] = mem[m + 1] * t1 + w1 * a;
        }
        if (act) rb[s * VD_ + j] = r0 + r1;
        __syncthreads();
    }
}

// ---------------------------------------------------------------------------
// Kernel 4: output head. One wave per token. Lanes 0..49 compute summary;
// butterfly reductions for theta/alpha/beta; lane 0 writes 4 probs.
// ---------------------------------------------------------------------------
__global__ __launch_bounds__(256) void k4_head(
    const int* __restrict__ q_data, const float* __restrict__ q_tab,
    const float* __restrict__ reads,
    const float* __restrict__ W_sum, const float* __restrict__ b_sum,
    const float* __restrict__ W_ab, const float* __restrict__ b_ab,
    const float* __restrict__ W_th, const float* __restrict__ b_th,
    const float* __restrict__ W_disc, const float* __restrict__ b_disc,
    float* __restrict__ out)
{
    const int wave = threadIdx.x >> 6;
    const int lane = threadIdx.x & 63;
    const int tok  = blockIdx.x * 4 + wave;

    const int q = q_data[tok];
    const float* qe = q_tab + (size_t)q * KD_;
    const float* rd = reads + (size_t)tok * VD_;

    float summary = 0.0f;
    if (lane < FD_) {
        float acc = b_sum[lane];
#pragma unroll 8
        for (int k = 0; k < VD_; ++k)
            acc += rd[k] * W_sum[k * FD_ + lane];
#pragma unroll 10
        for (int k = 0; k < KD_; ++k)
            acc += qe[k] * W_sum[(VD_ + k) * FD_ + lane];
        summary = tanhf(acc);
    }

    const float qv = (lane < KD_) ? qe[lane] : 0.0f;
    float v_ab = (lane < FD_) ? summary * W_ab[lane] : 0.0f;
    float v_d  = ((lane < FD_) ? summary * W_disc[lane] : 0.0f)
               + ((lane < KD_) ? qv * W_disc[FD_ + lane] : 0.0f);
    float v_t0 = (lane < KD_) ? qv * W_th[lane * 3 + 0] : 0.0f;
    float v_t1 = (lane < KD_) ? qv * W_th[lane * 3 + 1] : 0.0f;
    float v_t2 = (lane < KD_) ? qv * W_th[lane * 3 + 2] : 0.0f;

#pragma unroll
    for (int off = 32; off; off >>= 1) {
        v_ab += __shfl_xor(v_ab, off);
        v_d  += __shfl_xor(v_d,  off);
        v_t0 += __shfl_xor(v_t0, off);
        v_t1 += __shfl_xor(v_t1, off);
        v_t2 += __shfl_xor(v_t2, off);
    }

    if (lane == 0) {
        float theta = 3.0f * (v_ab + b_ab[0]);                      // ABILITY_SCALE
        float xd = v_d + b_disc[0];
        float alpha = fmaxf(xd, 0.0f) + log1pf(expf(-fabsf(xd)));   // softplus
        float beta0 = tanhf(v_t0 + b_th[0]);
        float beta1 = tanhf(v_t1 + b_th[1]);
        float beta2 = tanhf(v_t2 + b_th[2]);
        float c1 = alpha * (theta - beta0);
        float c2 = c1 + alpha * (theta - beta1);
        float c3 = c2 + alpha * (theta - beta2);
        float mx = fmaxf(fmaxf(0.0f, c1), fmaxf(c2, c3));
        float e0 = expf(0.0f - mx), e1 = expf(c1 - mx),
              e2 = expf(c2 - mx), e3 = expf(c3 - mx);
        float s = e0 + e1 + e2 + e3;
        float4 o = make_float4(e0 / s, e1 / s, e2 / s, e3 / s);
        *(float4*)&out[(size_t)tok * 4] = o;
    }
}

// ---------------------------------------------------------------------------
extern "C" void kernel_launch(void* const* d_in, const int* in_sizes, int n_in,
                              void* d_out, int out_size, void* d_ws, size_t ws_size,
                              hipStream_t stream) {
    const int*   q_data   = (const int*)  d_in[0];
    const int*   r_data   = (const int*)  d_in[1];
    const float* q_tab    = (const float*)d_in[2];
    const float* key_mem  = (const float*)d_in[3];
    const float* init_mem = (const float*)d_in[4];
    const float* W_qk     = (const float*)d_in[5];
    const float* b_qk     = (const float*)d_in[6];
    const float* W_v3     = (const float*)d_in[7];
    const float* b_v      = (const float*)d_in[8];
    const float* W_e      = (const float*)d_in[9];
    const float* b_e      = (const float*)d_in[10];
    const float* W_a      = (const float*)d_in[11];
    const float* b_a      = (const float*)d_in[12];
    const float* W_sum    = (const float*)d_in[13];
    const float* b_sum    = (const float*)d_in[14];
    const float* W_ab     = (const float*)d_in[15];
    const float* b_ab     = (const float*)d_in[16];
    const float* W_th     = (const float*)d_in[17];
    const float* b_th     = (const float*)d_in[18];
    const float* W_disc   = (const float*)d_in[19];
    const float* b_disc   = (const float*)d_in[20];

    float* ws    = (float*)d_ws;
    float* V     = ws;                       // T*VD = 10,240,000 floats
    float* reads = ws;                       // aliases V (V dead after k2)
    float* corr  = ws + (size_t)T_ * VD_;    // T*M  =  2,560,000
    float* erase = corr + (size_t)T_ * M_;   // T*VD
    float* add   = erase + (size_t)T_ * VD_; // T*VD
    // total: 33,280,000 floats = 133.12 MB of d_ws

    k1_embed<<<T_ / 4, 256, 0, stream>>>(q_data, r_data, q_tab, key_mem,
                                         W_qk, b_qk, W_v3, b_v, V, corr);
    k2_gemm<<<T_ / BT, 256, 0, stream>>>(V, W_e, b_e, W_a, b_a, erase, add);
    k3_scan<<<B_, 256, 0, stream>>>(init_mem, corr, erase, add, reads);
    k4_head<<<T_ / 4, 256, 0, stream>>>(q_data, q_tab, reads,
                                        W_sum, b_sum, W_ab, b_ab,
                                        W_th, b_th, W_disc, b_disc,
                                        (float*)d_out);
}

// Round 3
// 554.959 us; speedup vs baseline: 1.3879x; 1.3879x over previous
//
#include <hip/hip_runtime.h>
#include <math.h>

#define B_   256
#define S_   200
#define NQ_  400
#define K_   4
#define M_   50
#define KD_  50
#define VD_  200
#define FD_  50
#define T_   (B_*S_)   // 51200 tokens

// ---------------------------------------------------------------------------
// Kernel 1: per-token embeddings + correlation softmax. One wave (64 lanes)
// per token, 4 tokens per 256-thread block.
// ---------------------------------------------------------------------------
__global__ __launch_bounds__(256) void k1_embed(
    const int* __restrict__ q_data, const int* __restrict__ r_data,
    const float* __restrict__ q_tab, const float* __restrict__ key_mem,
    const float* __restrict__ W_qk, const float* __restrict__ b_qk,
    const float* __restrict__ W_v3, const float* __restrict__ b_v,
    float* __restrict__ V, float* __restrict__ corr)
{
    const int wave = threadIdx.x >> 6;
    const int lane = threadIdx.x & 63;
    const int tok  = blockIdx.x * 4 + wave;

    const int q = q_data[tok];
    const int r = r_data[tok];
    const float qmask = (q > 0) ? 1.0f : 0.0f;
    int idx = q - 1;
    if (idx < 0) idx = 0;
    if (idx > NQ_ - 1) idx = NQ_ - 1;

    float wc[K_];
#pragma unroll
    for (int k = 0; k < K_; ++k) {
        float dist = fabsf((float)k - (float)r) / (float)(K_ - 1);
        float w = 1.0f - dist;
        wc[k] = (w > 0.0f) ? w : 0.0f;
    }

    for (int j = lane; j < VD_; j += 64) {
        float s = 0.0f;
#pragma unroll
        for (int k = 0; k < K_; ++k)
            s += wc[k] * W_v3[((size_t)k * NQ_ + idx) * VD_ + j];
        V[(size_t)tok * VD_ + j] = b_v[j] + qmask * s;
    }

    __shared__ float sqk[4][KD_];
    const float* qe = q_tab + (size_t)q * KD_;
    if (lane < KD_) {
        float acc = b_qk[lane];
#pragma unroll 10
        for (int k = 0; k < KD_; ++k)
            acc += qe[k] * W_qk[k * KD_ + lane];
        sqk[wave][lane] = tanhf(acc);
    }
    __syncthreads();

    float c = -INFINITY;
    if (lane < M_) {
        float acc = 0.0f;
#pragma unroll 10
        for (int k = 0; k < KD_; ++k)
            acc += sqk[wave][k] * key_mem[lane * KD_ + k];
        c = acc;
    }
    float mx = c;
#pragma unroll
    for (int off = 32; off; off >>= 1) mx = fmaxf(mx, __shfl_xor(mx, off));
    float e = (lane < M_) ? expf(c - mx) : 0.0f;
    float sm = e;
#pragma unroll
    for (int off = 32; off; off >>= 1) sm += __shfl_xor(sm, off);
    if (lane < M_) corr[(size_t)tok * M_ + lane] = e / sm;
}

// ---------------------------------------------------------------------------
// Kernel 2 v2: register-blocked dual GEMM.
// Block: 40 tokens x 200 cols. Thread (ty,tx) = (tid/50, tid%50), tid<250:
// owns tokens t0..t0+7 (t0=ty*8) x cols c..c+3 (c=tx*4) x {erase,add}
// = 64 accumulators. Per K-step: 4 ds_read_b128 -> 64 FMAs (VALU-bound 2.7:1).
// ---------------------------------------------------------------------------
#define BT2 40
#define BK  25
__global__ __launch_bounds__(256) void k2_gemm(
    const float* __restrict__ V,
    const float* __restrict__ W_e, const float* __restrict__ b_e,
    const float* __restrict__ W_a, const float* __restrict__ b_a,
    float* __restrict__ erase, float* __restrict__ add)
{
    __shared__ float sWe[BK][VD_];   // 20 KB
    __shared__ float sWa[BK][VD_];   // 20 KB
    __shared__ float sVt[BK][BT2];   // 4 KB (V transposed: [k][token])

    const int tid = threadIdx.x;
    const int ty  = tid / 50;        // 0..4 token-group
    const int tx  = tid % 50;        // 0..49 col-group
    const bool act = (tid < 250);
    const int tok0 = blockIdx.x * BT2;
    const int c  = tx * 4;
    const int t0 = ty * 8;

    float accE[8][4], accA[8][4];
#pragma unroll
    for (int i = 0; i < 8; ++i)
#pragma unroll
        for (int l = 0; l < 4; ++l) { accE[i][l] = 0.f; accA[i][l] = 0.f; }

    for (int kt = 0; kt < VD_; kt += BK) {
        __syncthreads();
        // stage W tiles (float4, coalesced)
        for (int i = tid; i < BK * (VD_ / 4); i += 256) {
            int row = i / (VD_ / 4), c4 = (i % (VD_ / 4)) * 4;
            *(float4*)&sWe[row][c4] = *(const float4*)&W_e[(kt + row) * VD_ + c4];
            *(float4*)&sWa[row][c4] = *(const float4*)&W_a[(kt + row) * VD_ + c4];
        }
        // stage V transposed (L1 absorbs the strided re-reads)
        for (int i = tid; i < BK * BT2; i += 256) {
            int t = i % BT2, kk = i / BT2;
            sVt[kk][t] = V[(size_t)(tok0 + t) * VD_ + kt + kk];
        }
        __syncthreads();

        if (act) {
#pragma unroll 5
            for (int kk = 0; kk < BK; ++kk) {
                float4 we = *(const float4*)&sWe[kk][c];
                float4 wa = *(const float4*)&sWa[kk][c];
                float4 v0 = *(const float4*)&sVt[kk][t0];
                float4 v1 = *(const float4*)&sVt[kk][t0 + 4];
                float vv[8] = {v0.x, v0.y, v0.z, v0.w, v1.x, v1.y, v1.z, v1.w};
#pragma unroll
                for (int i = 0; i < 8; ++i) {
                    accE[i][0] += vv[i] * we.x; accE[i][1] += vv[i] * we.y;
                    accE[i][2] += vv[i] * we.z; accE[i][3] += vv[i] * we.w;
                    accA[i][0] += vv[i] * wa.x; accA[i][1] += vv[i] * wa.y;
                    accA[i][2] += vv[i] * wa.z; accA[i][3] += vv[i] * wa.w;
                }
            }
        }
    }

    if (act) {
        const float4 be = *(const float4*)&b_e[c];
        const float4 ba = *(const float4*)&b_a[c];
#pragma unroll
        for (int i = 0; i < 8; ++i) {
            const size_t tok = tok0 + t0 + i;
            float4 eo, ao;
            eo.x = 1.0f / (1.0f + expf(-(accE[i][0] + be.x)));
            eo.y = 1.0f / (1.0f + expf(-(accE[i][1] + be.y)));
            eo.z = 1.0f / (1.0f + expf(-(accE[i][2] + be.z)));
            eo.w = 1.0f / (1.0f + expf(-(accE[i][3] + be.w)));
            ao.x = tanhf(accA[i][0] + ba.x);
            ao.y = tanhf(accA[i][1] + ba.y);
            ao.z = tanhf(accA[i][2] + ba.z);
            ao.w = tanhf(accA[i][3] + ba.w);
            *(float4*)&erase[tok * VD_ + c] = eo;
            *(float4*)&add[tok * VD_ + c]   = ao;
        }
    }
}

// ---------------------------------------------------------------------------
// Kernel 3 v2: sequential scan with software pipelining. One block per batch;
// thread j owns memory column j in registers. Step s+1's e/a (registers) and
// corr row (double-buffered LDS) are prefetched before computing step s;
// one barrier per step.
// ---------------------------------------------------------------------------
__global__ __launch_bounds__(256) void k3_scan(
    const float* __restrict__ init_mem,
    const float* __restrict__ corr, const float* __restrict__ erase,
    const float* __restrict__ add, float* __restrict__ reads)
{
    const int b = blockIdx.x;
    const int j = threadIdx.x;
    const bool act = (j < VD_);

    float mem[M_];
    if (act) {
#pragma unroll
        for (int m = 0; m < M_; ++m) mem[m] = init_mem[m * VD_ + j];
    }

    __shared__ float wsh[2][M_];
    const float* cb = corr  + (size_t)b * S_ * M_;
    const float* eb = erase + (size_t)b * S_ * VD_;
    const float* ab = add   + (size_t)b * S_ * VD_;
    float* rb       = reads + (size_t)b * S_ * VD_;

    float e = 0.f, a = 0.f;
    if (act) { e = eb[j]; a = ab[j]; }
    if (j < M_) wsh[0][j] = cb[j];
    __syncthreads();

    for (int s = 0; s < S_; ++s) {
        float en = 0.f, an = 0.f;
        if (s + 1 < S_) {
            if (act) { en = eb[(s + 1) * VD_ + j]; an = ab[(s + 1) * VD_ + j]; }
            if (j < M_) wsh[(s + 1) & 1][j] = cb[(s + 1) * M_ + j];
        }
        const float* w = wsh[s & 1];
        float r0 = 0.f, r1 = 0.f;
#pragma unroll
        for (int m = 0; m < M_; m += 2) {
            float w0 = w[m], w1 = w[m + 1];
            r0 += w0 * mem[m];
            mem[m] = mem[m] * (1.0f - w0 * e) + w0 * a;
            r1 += w1 * mem[m + 1];
            mem[m + 1] = mem[m + 1] * (1.0f - w1 * e) + w1 * a;
        }
        if (act) rb[s * VD_ + j] = r0 + r1;
        __syncthreads();
        e = en; a = an;
    }
}

// ---------------------------------------------------------------------------
// Kernel 4: output head. One wave per token.
// ---------------------------------------------------------------------------
__global__ __launch_bounds__(256) void k4_head(
    const int* __restrict__ q_data, const float* __restrict__ q_tab,
    const float* __restrict__ reads,
    const float* __restrict__ W_sum, const float* __restrict__ b_sum,
    const float* __restrict__ W_ab, const float* __restrict__ b_ab,
    const float* __restrict__ W_th, const float* __restrict__ b_th,
    const float* __restrict__ W_disc, const float* __restrict__ b_disc,
    float* __restrict__ out)
{
    const int wave = threadIdx.x >> 6;
    const int lane = threadIdx.x & 63;
    const int tok  = blockIdx.x * 4 + wave;

    const int q = q_data[tok];
    const float* qe = q_tab + (size_t)q * KD_;
    const float* rd = reads + (size_t)tok * VD_;

    float summary = 0.0f;
    if (lane < FD_) {
        float acc = b_sum[lane];
#pragma unroll 8
        for (int k = 0; k < VD_; ++k)
            acc += rd[k] * W_sum[k * FD_ + lane];
#pragma unroll 10
        for (int k = 0; k < KD_; ++k)
            acc += qe[k] * W_sum[(VD_ + k) * FD_ + lane];
        summary = tanhf(acc);
    }

    const float qv = (lane < KD_) ? qe[lane] : 0.0f;
    float v_ab = (lane < FD_) ? summary * W_ab[lane] : 0.0f;
    float v_d  = ((lane < FD_) ? summary * W_disc[lane] : 0.0f)
               + ((lane < KD_) ? qv * W_disc[FD_ + lane] : 0.0f);
    float v_t0 = (lane < KD_) ? qv * W_th[lane * 3 + 0] : 0.0f;
    float v_t1 = (lane < KD_) ? qv * W_th[lane * 3 + 1] : 0.0f;
    float v_t2 = (lane < KD_) ? qv * W_th[lane * 3 + 2] : 0.0f;

#pragma unroll
    for (int off = 32; off; off >>= 1) {
        v_ab += __shfl_xor(v_ab, off);
        v_d  += __shfl_xor(v_d,  off);
        v_t0 += __shfl_xor(v_t0, off);
        v_t1 += __shfl_xor(v_t1, off);
        v_t2 += __shfl_xor(v_t2, off);
    }

    if (lane == 0) {
        float theta = 3.0f * (v_ab + b_ab[0]);
        float xd = v_d + b_disc[0];
        float alpha = fmaxf(xd, 0.0f) + log1pf(expf(-fabsf(xd)));
        float beta0 = tanhf(v_t0 + b_th[0]);
        float beta1 = tanhf(v_t1 + b_th[1]);
        float beta2 = tanhf(v_t2 + b_th[2]);
        float c1 = alpha * (theta - beta0);
        float c2 = c1 + alpha * (theta - beta1);
        float c3 = c2 + alpha * (theta - beta2);
        float mx = fmaxf(fmaxf(0.0f, c1), fmaxf(c2, c3));
        float e0 = expf(0.0f - mx), e1 = expf(c1 - mx),
              e2 = expf(c2 - mx), e3 = expf(c3 - mx);
        float s = e0 + e1 + e2 + e3;
        float4 o = make_float4(e0 / s, e1 / s, e2 / s, e3 / s);
        *(float4*)&out[(size_t)tok * 4] = o;
    }
}

// ---------------------------------------------------------------------------
extern "C" void kernel_launch(void* const* d_in, const int* in_sizes, int n_in,
                              void* d_out, int out_size, void* d_ws, size_t ws_size,
                              hipStream_t stream) {
    const int*   q_data   = (const int*)  d_in[0];
    const int*   r_data   = (const int*)  d_in[1];
    const float* q_tab    = (const float*)d_in[2];
    const float* key_mem  = (const float*)d_in[3];
    const float* init_mem = (const float*)d_in[4];
    const float* W_qk     = (const float*)d_in[5];
    const float* b_qk     = (const float*)d_in[6];
    const float* W_v3     = (const float*)d_in[7];
    const float* b_v      = (const float*)d_in[8];
    const float* W_e      = (const float*)d_in[9];
    const float* b_e      = (const float*)d_in[10];
    const float* W_a      = (const float*)d_in[11];
    const float* b_a      = (const float*)d_in[12];
    const float* W_sum    = (const float*)d_in[13];
    const float* b_sum    = (const float*)d_in[14];
    const float* W_ab     = (const float*)d_in[15];
    const float* b_ab     = (const float*)d_in[16];
    const float* W_th     = (const float*)d_in[17];
    const float* b_th     = (const float*)d_in[18];
    const float* W_disc   = (const float*)d_in[19];
    const float* b_disc   = (const float*)d_in[20];

    float* ws    = (float*)d_ws;
    float* V     = ws;                       // T*VD
    float* reads = ws;                       // aliases V (V dead after k2)
    float* corr  = ws + (size_t)T_ * VD_;    // T*M
    float* erase = corr + (size_t)T_ * M_;   // T*VD
    float* add   = erase + (size_t)T_ * VD_; // T*VD

    k1_embed<<<T_ / 4, 256, 0, stream>>>(q_data, r_data, q_tab, key_mem,
                                         W_qk, b_qk, W_v3, b_v, V, corr);
    k2_gemm<<<T_ / BT2, 256, 0, stream>>>(V, W_e, b_e, W_a, b_a, erase, add);
    k3_scan<<<B_, 256, 0, stream>>>(init_mem, corr, erase, add, reads);
    k4_head<<<T_ / 4, 256, 0, stream>>>(q_data, q_tab, reads,
                                        W_sum, b_sum, W_ab, b_ab,
                                        W_th, b_th, W_disc, b_disc,
                                        (float*)d_out);
}

// Round 4
// 469.699 us; speedup vs baseline: 1.6398x; 1.1815x over previous
//
#include <hip/hip_runtime.h>
#include <math.h>

#define B_   256
#define S_   200
#define NQ_  400
#define K_   4
#define M_   50
#define KD_  50
#define VD_  200
#define FD_  50
#define T_   (B_*S_)   // 51200 tokens

// ---------------------------------------------------------------------------
// Kernel 1: per-token embeddings + correlation softmax. One wave per token.
// ---------------------------------------------------------------------------
__global__ __launch_bounds__(256) void k1_embed(
    const int* __restrict__ q_data, const int* __restrict__ r_data,
    const float* __restrict__ q_tab, const float* __restrict__ key_mem,
    const float* __restrict__ W_qk, const float* __restrict__ b_qk,
    const float* __restrict__ W_v3, const float* __restrict__ b_v,
    float* __restrict__ V, float* __restrict__ corr)
{
    const int wave = threadIdx.x >> 6;
    const int lane = threadIdx.x & 63;
    const int tok  = blockIdx.x * 4 + wave;

    const int q = q_data[tok];
    const int r = r_data[tok];
    const float qmask = (q > 0) ? 1.0f : 0.0f;
    int idx = q - 1;
    if (idx < 0) idx = 0;
    if (idx > NQ_ - 1) idx = NQ_ - 1;

    float wc[K_];
#pragma unroll
    for (int k = 0; k < K_; ++k) {
        float dist = fabsf((float)k - (float)r) / (float)(K_ - 1);
        float w = 1.0f - dist;
        wc[k] = (w > 0.0f) ? w : 0.0f;
    }

    for (int j = lane; j < VD_; j += 64) {
        float s = 0.0f;
#pragma unroll
        for (int k = 0; k < K_; ++k)
            s += wc[k] * W_v3[((size_t)k * NQ_ + idx) * VD_ + j];
        V[(size_t)tok * VD_ + j] = b_v[j] + qmask * s;
    }

    __shared__ float sqk[4][KD_];
    const float* qe = q_tab + (size_t)q * KD_;
    if (lane < KD_) {
        float acc = b_qk[lane];
#pragma unroll 10
        for (int k = 0; k < KD_; ++k)
            acc += qe[k] * W_qk[k * KD_ + lane];
        sqk[wave][lane] = tanhf(acc);
    }
    __syncthreads();

    float c = -INFINITY;
    if (lane < M_) {
        float acc = 0.0f;
#pragma unroll 10
        for (int k = 0; k < KD_; ++k)
            acc += sqk[wave][k] * key_mem[lane * KD_ + k];
        c = acc;
    }
    float mx = c;
#pragma unroll
    for (int off = 32; off; off >>= 1) mx = fmaxf(mx, __shfl_xor(mx, off));
    float e = (lane < M_) ? expf(c - mx) : 0.0f;
    float sm = e;
#pragma unroll
    for (int off = 32; off; off >>= 1) sm += __shfl_xor(sm, off);
    if (lane < M_) corr[(size_t)tok * M_ + lane] = e / sm;
}

// ---------------------------------------------------------------------------
// Kernel 2: register-blocked dual GEMM (unchanged from round 2).
// ---------------------------------------------------------------------------
#define BT2 40
#define BK  25
__global__ __launch_bounds__(256) void k2_gemm(
    const float* __restrict__ V,
    const float* __restrict__ W_e, const float* __restrict__ b_e,
    const float* __restrict__ W_a, const float* __restrict__ b_a,
    float* __restrict__ erase, float* __restrict__ add)
{
    __shared__ float sWe[BK][VD_];
    __shared__ float sWa[BK][VD_];
    __shared__ float sVt[BK][BT2];

    const int tid = threadIdx.x;
    const int ty  = tid / 50;
    const int tx  = tid % 50;
    const bool act = (tid < 250);
    const int tok0 = blockIdx.x * BT2;
    const int c  = tx * 4;
    const int t0 = ty * 8;

    float accE[8][4], accA[8][4];
#pragma unroll
    for (int i = 0; i < 8; ++i)
#pragma unroll
        for (int l = 0; l < 4; ++l) { accE[i][l] = 0.f; accA[i][l] = 0.f; }

    for (int kt = 0; kt < VD_; kt += BK) {
        __syncthreads();
        for (int i = tid; i < BK * (VD_ / 4); i += 256) {
            int row = i / (VD_ / 4), c4 = (i % (VD_ / 4)) * 4;
            *(float4*)&sWe[row][c4] = *(const float4*)&W_e[(kt + row) * VD_ + c4];
            *(float4*)&sWa[row][c4] = *(const float4*)&W_a[(kt + row) * VD_ + c4];
        }
        for (int i = tid; i < BK * BT2; i += 256) {
            int t = i % BT2, kk = i / BT2;
            sVt[kk][t] = V[(size_t)(tok0 + t) * VD_ + kt + kk];
        }
        __syncthreads();

        if (act) {
#pragma unroll 5
            for (int kk = 0; kk < BK; ++kk) {
                float4 we = *(const float4*)&sWe[kk][c];
                float4 wa = *(const float4*)&sWa[kk][c];
                float4 v0 = *(const float4*)&sVt[kk][t0];
                float4 v1 = *(const float4*)&sVt[kk][t0 + 4];
                float vv[8] = {v0.x, v0.y, v0.z, v0.w, v1.x, v1.y, v1.z, v1.w};
#pragma unroll
                for (int i = 0; i < 8; ++i) {
                    accE[i][0] += vv[i] * we.x; accE[i][1] += vv[i] * we.y;
                    accE[i][2] += vv[i] * we.z; accE[i][3] += vv[i] * we.w;
                    accA[i][0] += vv[i] * wa.x; accA[i][1] += vv[i] * wa.y;
                    accA[i][2] += vv[i] * wa.z; accA[i][3] += vv[i] * wa.w;
                }
            }
        }
    }

    if (act) {
        const float4 be = *(const float4*)&b_e[c];
        const float4 ba = *(const float4*)&b_a[c];
#pragma unroll
        for (int i = 0; i < 8; ++i) {
            const size_t tok = tok0 + t0 + i;
            float4 eo, ao;
            eo.x = 1.0f / (1.0f + expf(-(accE[i][0] + be.x)));
            eo.y = 1.0f / (1.0f + expf(-(accE[i][1] + be.y)));
            eo.z = 1.0f / (1.0f + expf(-(accE[i][2] + be.z)));
            eo.w = 1.0f / (1.0f + expf(-(accE[i][3] + be.w)));
            ao.x = tanhf(accA[i][0] + ba.x);
            ao.y = tanhf(accA[i][1] + ba.y);
            ao.z = tanhf(accA[i][2] + ba.z);
            ao.w = tanhf(accA[i][3] + ba.w);
            *(float4*)&erase[tok * VD_ + c] = eo;
            *(float4*)&add[tok * VD_ + c]   = ao;
        }
    }
}

// ---------------------------------------------------------------------------
// Kernel 3: pipelined sequential scan (unchanged from round 2).
// ---------------------------------------------------------------------------
__global__ __launch_bounds__(256) void k3_scan(
    const float* __restrict__ init_mem,
    const float* __restrict__ corr, const float* __restrict__ erase,
    const float* __restrict__ add, float* __restrict__ reads)
{
    const int b = blockIdx.x;
    const int j = threadIdx.x;
    const bool act = (j < VD_);

    float mem[M_];
    if (act) {
#pragma unroll
        for (int m = 0; m < M_; ++m) mem[m] = init_mem[m * VD_ + j];
    }

    __shared__ float wsh[2][M_];
    const float* cb = corr  + (size_t)b * S_ * M_;
    const float* eb = erase + (size_t)b * S_ * VD_;
    const float* ab = add   + (size_t)b * S_ * VD_;
    float* rb       = reads + (size_t)b * S_ * VD_;

    float e = 0.f, a = 0.f;
    if (act) { e = eb[j]; a = ab[j]; }
    if (j < M_) wsh[0][j] = cb[j];
    __syncthreads();

    for (int s = 0; s < S_; ++s) {
        float en = 0.f, an = 0.f;
        if (s + 1 < S_) {
            if (act) { en = eb[(s + 1) * VD_ + j]; an = ab[(s + 1) * VD_ + j]; }
            if (j < M_) wsh[(s + 1) & 1][j] = cb[(s + 1) * M_ + j];
        }
        const float* w = wsh[s & 1];
        float r0 = 0.f, r1 = 0.f;
#pragma unroll
        for (int m = 0; m < M_; m += 2) {
            float w0 = w[m], w1 = w[m + 1];
            r0 += w0 * mem[m];
            mem[m] = mem[m] * (1.0f - w0 * e) + w0 * a;
            r1 += w1 * mem[m + 1];
            mem[m + 1] = mem[m + 1] * (1.0f - w1 * e) + w1 * a;
        }
        if (act) rb[s * VD_ + j] = r0 + r1;
        __syncthreads();
        e = en; a = an;
    }
}

// ---------------------------------------------------------------------------
// Kernel 4 v2: summary GEMM (LDS-tiled, register-blocked) + fused head.
// Block = 80 tokens. A = [reads | q_emb] (K=250) staged transposed in
// sAt[25][84] (pad 84: 16B-aligned b128 rows, bounded write conflicts).
// Thread (ty,tx)= (tid/25? no: ty=tid/25 in [0,10)) -> 8 tokens x 2 cols.
// Then summary -> sSum LDS, head phase = 4 waves x 20 tokens, shfl reduces.
// ---------------------------------------------------------------------------
#define BT4 80
#define KA  250
__global__ __launch_bounds__(256) void k4_head(
    const int* __restrict__ q_data, const float* __restrict__ q_tab,
    const float* __restrict__ reads,
    const float* __restrict__ W_sum, const float* __restrict__ b_sum,
    const float* __restrict__ W_ab, const float* __restrict__ b_ab,
    const float* __restrict__ W_th, const float* __restrict__ b_th,
    const float* __restrict__ W_disc, const float* __restrict__ b_disc,
    float* __restrict__ out)
{
    __shared__ __align__(16) float sAt[BK][84];    // A^T tile, pad 84
    __shared__ __align__(16) float sW[BK][52];     // W_sum tile, pad 52
    __shared__ __align__(16) float sSum[BT4][52];  // summary, pad 52
    __shared__ int sQ[BT4];

    const int tid  = threadIdx.x;
    const int tok0 = blockIdx.x * BT4;

    const int ty = tid / 25;        // 0..9 (for tid<250): token group of 8
    const int tx = tid % 25;        // col pair: cols 2tx, 2tx+1
    const bool act = (tid < 250);
    const int t0 = ty * 8;

    if (tid < BT4) sQ[tid] = q_data[tok0 + tid];

    float acc[8][2];
#pragma unroll
    for (int i = 0; i < 8; ++i) { acc[i][0] = 0.f; acc[i][1] = 0.f; }

    for (int kt = 0; kt < KA; kt += BK) {
        __syncthreads();
        // stage A^T tile: coalesced 25-float runs per token row
        for (int i = tid; i < BT4 * BK; i += 256) {
            int t = i / BK, kk = i % BK;
            float v;
            if (kt < VD_) v = reads[(size_t)(tok0 + t) * VD_ + kt + kk];
            else          v = q_tab[(size_t)sQ[t] * KD_ + (kt - VD_) + kk];
            sAt[kk][t] = v;
        }
        // stage W_sum tile [25][50]
        for (int i = tid; i < BK * FD_; i += 256) {
            int kk = i / FD_, col = i % FD_;
            sW[kk][col] = W_sum[(size_t)(kt + kk) * FD_ + col];
        }
        __syncthreads();

        if (act) {
#pragma unroll 5
            for (int kk = 0; kk < BK; ++kk) {
                float2 w = *(const float2*)&sW[kk][2 * tx];
                float4 a0 = *(const float4*)&sAt[kk][t0];
                float4 a1 = *(const float4*)&sAt[kk][t0 + 4];
                float av[8] = {a0.x, a0.y, a0.z, a0.w, a1.x, a1.y, a1.z, a1.w};
#pragma unroll
                for (int i = 0; i < 8; ++i) {
                    acc[i][0] += av[i] * w.x;
                    acc[i][1] += av[i] * w.y;
                }
            }
        }
    }

    // summary = tanh(acc + b_sum) -> LDS
    if (act) {
        const float b0 = b_sum[2 * tx], b1 = b_sum[2 * tx + 1];
#pragma unroll
        for (int i = 0; i < 8; ++i) {
            sSum[t0 + i][2 * tx]     = tanhf(acc[i][0] + b0);
            sSum[t0 + i][2 * tx + 1] = tanhf(acc[i][1] + b1);
        }
    }
    __syncthreads();

    // head phase: wave w handles tokens w*20 .. w*20+19
    const int wv   = tid >> 6;
    const int lane = tid & 63;
    for (int lt = wv * 20; lt < wv * 20 + 20; ++lt) {
        const int tok = tok0 + lt;
        const float s  = (lane < FD_) ? sSum[lt][lane] : 0.0f;
        const int  qi  = sQ[lt];
        const float qv = (lane < KD_) ? q_tab[(size_t)qi * KD_ + lane] : 0.0f;

        float v_ab = (lane < FD_) ? s * W_ab[lane] : 0.0f;
        float v_d  = ((lane < FD_) ? s * W_disc[lane] : 0.0f)
                   + ((lane < KD_) ? qv * W_disc[FD_ + lane] : 0.0f);
        float v_t0 = (lane < KD_) ? qv * W_th[lane * 3 + 0] : 0.0f;
        float v_t1 = (lane < KD_) ? qv * W_th[lane * 3 + 1] : 0.0f;
        float v_t2 = (lane < KD_) ? qv * W_th[lane * 3 + 2] : 0.0f;

#pragma unroll
        for (int off = 32; off; off >>= 1) {
            v_ab += __shfl_xor(v_ab, off);
            v_d  += __shfl_xor(v_d,  off);
            v_t0 += __shfl_xor(v_t0, off);
            v_t1 += __shfl_xor(v_t1, off);
            v_t2 += __shfl_xor(v_t2, off);
        }

        if (lane == 0) {
            float theta = 3.0f * (v_ab + b_ab[0]);
            float xd = v_d + b_disc[0];
            float alpha = fmaxf(xd, 0.0f) + log1pf(expf(-fabsf(xd)));
            float beta0 = tanhf(v_t0 + b_th[0]);
            float beta1 = tanhf(v_t1 + b_th[1]);
            float beta2 = tanhf(v_t2 + b_th[2]);
            float c1 = alpha * (theta - beta0);
            float c2 = c1 + alpha * (theta - beta1);
            float c3 = c2 + alpha * (theta - beta2);
            float mx = fmaxf(fmaxf(0.0f, c1), fmaxf(c2, c3));
            float e0 = expf(0.0f - mx), e1 = expf(c1 - mx),
                  e2 = expf(c2 - mx), e3 = expf(c3 - mx);
            float s4 = e0 + e1 + e2 + e3;
            float4 o = make_float4(e0 / s4, e1 / s4, e2 / s4, e3 / s4);
            *(float4*)&out[(size_t)tok * 4] = o;
        }
    }
}

// ---------------------------------------------------------------------------
extern "C" void kernel_launch(void* const* d_in, const int* in_sizes, int n_in,
                              void* d_out, int out_size, void* d_ws, size_t ws_size,
                              hipStream_t stream) {
    const int*   q_data   = (const int*)  d_in[0];
    const int*   r_data   = (const int*)  d_in[1];
    const float* q_tab    = (const float*)d_in[2];
    const float* key_mem  = (const float*)d_in[3];
    const float* init_mem = (const float*)d_in[4];
    const float* W_qk     = (const float*)d_in[5];
    const float* b_qk     = (const float*)d_in[6];
    const float* W_v3     = (const float*)d_in[7];
    const float* b_v      = (const float*)d_in[8];
    const float* W_e      = (const float*)d_in[9];
    const float* b_e      = (const float*)d_in[10];
    const float* W_a      = (const float*)d_in[11];
    const float* b_a      = (const float*)d_in[12];
    const float* W_sum    = (const float*)d_in[13];
    const float* b_sum    = (const float*)d_in[14];
    const float* W_ab     = (const float*)d_in[15];
    const float* b_ab     = (const float*)d_in[16];
    const float* W_th     = (const float*)d_in[17];
    const float* b_th     = (const float*)d_in[18];
    const float* W_disc   = (const float*)d_in[19];
    const float* b_disc   = (const float*)d_in[20];

    float* ws    = (float*)d_ws;
    float* V     = ws;                       // T*VD
    float* reads = ws;                       // aliases V (V dead after k2)
    float* corr  = ws + (size_t)T_ * VD_;    // T*M
    float* erase = corr + (size_t)T_ * M_;   // T*VD
    float* add   = erase + (size_t)T_ * VD_; // T*VD

    k1_embed<<<T_ / 4, 256, 0, stream>>>(q_data, r_data, q_tab, key_mem,
                                         W_qk, b_qk, W_v3, b_v, V, corr);
    k2_gemm<<<T_ / BT2, 256, 0, stream>>>(V, W_e, b_e, W_a, b_a, erase, add);
    k3_scan<<<B_, 256, 0, stream>>>(init_mem, corr, erase, add, reads);
    k4_head<<<T_ / BT4, 256, 0, stream>>>(q_data, q_tab, reads,
                                          W_sum, b_sum, W_ab, b_ab,
                                          W_th, b_th, W_disc, b_disc,
                                          (float*)d_out);
}

// Round 5
// 438.020 us; speedup vs baseline: 1.7584x; 1.0723x over previous
//
#include <hip/hip_runtime.h>
#include <math.h>

#define B_   256
#define S_   200
#define NQ_  400
#define K_   4
#define M_   50
#define KD_  50
#define VD_  200
#define FD_  50
#define T_   (B_*S_)   // 51200 tokens

// ---------------------------------------------------------------------------
// Kernel 1: per-token embeddings + correlation softmax. One wave per token.
// ---------------------------------------------------------------------------
__global__ __launch_bounds__(256) void k1_embed(
    const int* __restrict__ q_data, const int* __restrict__ r_data,
    const float* __restrict__ q_tab, const float* __restrict__ key_mem,
    const float* __restrict__ W_qk, const float* __restrict__ b_qk,
    const float* __restrict__ W_v3, const float* __restrict__ b_v,
    float* __restrict__ V, float* __restrict__ corr)
{
    const int wave = threadIdx.x >> 6;
    const int lane = threadIdx.x & 63;
    const int tok  = blockIdx.x * 4 + wave;

    const int q = q_data[tok];
    const int r = r_data[tok];
    const float qmask = (q > 0) ? 1.0f : 0.0f;
    int idx = q - 1;
    if (idx < 0) idx = 0;
    if (idx > NQ_ - 1) idx = NQ_ - 1;

    float wc[K_];
#pragma unroll
    for (int k = 0; k < K_; ++k) {
        float dist = fabsf((float)k - (float)r) / (float)(K_ - 1);
        float w = 1.0f - dist;
        wc[k] = (w > 0.0f) ? w : 0.0f;
    }

    for (int j = lane; j < VD_; j += 64) {
        float s = 0.0f;
#pragma unroll
        for (int k = 0; k < K_; ++k)
            s += wc[k] * W_v3[((size_t)k * NQ_ + idx) * VD_ + j];
        V[(size_t)tok * VD_ + j] = b_v[j] + qmask * s;
    }

    __shared__ float sqk[4][KD_];
    const float* qe = q_tab + (size_t)q * KD_;
    if (lane < KD_) {
        float acc = b_qk[lane];
#pragma unroll 10
        for (int k = 0; k < KD_; ++k)
            acc += qe[k] * W_qk[k * KD_ + lane];
        sqk[wave][lane] = tanhf(acc);
    }
    __syncthreads();

    float c = -INFINITY;
    if (lane < M_) {
        float acc = 0.0f;
#pragma unroll 10
        for (int k = 0; k < KD_; ++k)
            acc += sqk[wave][k] * key_mem[lane * KD_ + k];
        c = acc;
    }
    float mx = c;
#pragma unroll
    for (int off = 32; off; off >>= 1) mx = fmaxf(mx, __shfl_xor(mx, off));
    float e = (lane < M_) ? expf(c - mx) : 0.0f;
    float sm = e;
#pragma unroll
    for (int off = 32; off; off >>= 1) sm += __shfl_xor(sm, off);
    if (lane < M_) corr[(size_t)tok * M_ + lane] = e / sm;
}

// ---------------------------------------------------------------------------
// Kernel 2: register-blocked dual GEMM (unchanged).
// ---------------------------------------------------------------------------
#define BT2 40
#define BK  25
__global__ __launch_bounds__(256) void k2_gemm(
    const float* __restrict__ V,
    const float* __restrict__ W_e, const float* __restrict__ b_e,
    const float* __restrict__ W_a, const float* __restrict__ b_a,
    float* __restrict__ erase, float* __restrict__ add)
{
    __shared__ float sWe[BK][VD_];
    __shared__ float sWa[BK][VD_];
    __shared__ float sVt[BK][BT2];

    const int tid = threadIdx.x;
    const int ty  = tid / 50;
    const int tx  = tid % 50;
    const bool act = (tid < 250);
    const int tok0 = blockIdx.x * BT2;
    const int c  = tx * 4;
    const int t0 = ty * 8;

    float accE[8][4], accA[8][4];
#pragma unroll
    for (int i = 0; i < 8; ++i)
#pragma unroll
        for (int l = 0; l < 4; ++l) { accE[i][l] = 0.f; accA[i][l] = 0.f; }

    for (int kt = 0; kt < VD_; kt += BK) {
        __syncthreads();
        for (int i = tid; i < BK * (VD_ / 4); i += 256) {
            int row = i / (VD_ / 4), c4 = (i % (VD_ / 4)) * 4;
            *(float4*)&sWe[row][c4] = *(const float4*)&W_e[(kt + row) * VD_ + c4];
            *(float4*)&sWa[row][c4] = *(const float4*)&W_a[(kt + row) * VD_ + c4];
        }
        for (int i = tid; i < BK * BT2; i += 256) {
            int t = i % BT2, kk = i / BT2;
            sVt[kk][t] = V[(size_t)(tok0 + t) * VD_ + kt + kk];
        }
        __syncthreads();

        if (act) {
#pragma unroll 5
            for (int kk = 0; kk < BK; ++kk) {
                float4 we = *(const float4*)&sWe[kk][c];
                float4 wa = *(const float4*)&sWa[kk][c];
                float4 v0 = *(const float4*)&sVt[kk][t0];
                float4 v1 = *(const float4*)&sVt[kk][t0 + 4];
                float vv[8] = {v0.x, v0.y, v0.z, v0.w, v1.x, v1.y, v1.z, v1.w};
#pragma unroll
                for (int i = 0; i < 8; ++i) {
                    accE[i][0] += vv[i] * we.x; accE[i][1] += vv[i] * we.y;
                    accE[i][2] += vv[i] * we.z; accE[i][3] += vv[i] * we.w;
                    accA[i][0] += vv[i] * wa.x; accA[i][1] += vv[i] * wa.y;
                    accA[i][2] += vv[i] * wa.z; accA[i][3] += vv[i] * wa.w;
                }
            }
        }
    }

    if (act) {
        const float4 be = *(const float4*)&b_e[c];
        const float4 ba = *(const float4*)&b_a[c];
#pragma unroll
        for (int i = 0; i < 8; ++i) {
            const size_t tok = tok0 + t0 + i;
            float4 eo, ao;
            eo.x = 1.0f / (1.0f + expf(-(accE[i][0] + be.x)));
            eo.y = 1.0f / (1.0f + expf(-(accE[i][1] + be.y)));
            eo.z = 1.0f / (1.0f + expf(-(accE[i][2] + be.z)));
            eo.w = 1.0f / (1.0f + expf(-(accE[i][3] + be.w)));
            ao.x = tanhf(accA[i][0] + ba.x);
            ao.y = tanhf(accA[i][1] + ba.y);
            ao.z = tanhf(accA[i][2] + ba.z);
            ao.w = tanhf(accA[i][3] + ba.w);
            *(float4*)&erase[tok * VD_ + c] = eo;
            *(float4*)&add[tok * VD_ + c]   = ao;
        }
    }
}

// ---------------------------------------------------------------------------
// Kernel 3 v3: scan with 4-deep register pipeline + decoupled corr staging.
// TLP is capped at 1 wave/SIMD (800 total waves < 1024 SIMDs), so latency
// must be hidden by prefetch depth: e/a rows s..s+3 live in registers
// (consumed ~2 iterations after issue); corr rows go global->reg (2 steps
// early) then reg->LDS 4-ring (1 iteration later) so ds_write never stalls
// on a fresh load. Inner loop is 3 FMA per memory slot. One barrier / 2 steps.
// ---------------------------------------------------------------------------
__global__ __launch_bounds__(256) void k3_scan(
    const float* __restrict__ init_mem,
    const float* __restrict__ corr, const float* __restrict__ erase,
    const float* __restrict__ add, float* __restrict__ reads)
{
    const int b = blockIdx.x;
    const int j = threadIdx.x;
    const bool act = (j < VD_);

    float mem[M_];
    if (act) {
#pragma unroll
        for (int m = 0; m < M_; ++m) mem[m] = init_mem[m * VD_ + j];
    }

    __shared__ float wsh[4][M_];   // ring: buffer (s&3) holds corr row s
    const float* cb = corr  + (size_t)b * S_ * M_;
    const float* eb = erase + (size_t)b * S_ * VD_;
    const float* ab = add   + (size_t)b * S_ * VD_;
    float* rb       = reads + (size_t)b * S_ * VD_;

    // prologue: e/a rows 0..3 in regs; corr rows 0,1 in LDS; rows 2,3 in regs
    float e0=0,a0=0,e1=0,a1=0,e2=0,a2=0,e3=0,a3=0;
    if (act) {
        e0 = eb[0*VD_+j]; a0 = ab[0*VD_+j];
        e1 = eb[1*VD_+j]; a1 = ab[1*VD_+j];
        e2 = eb[2*VD_+j]; a2 = ab[2*VD_+j];
        e3 = eb[3*VD_+j]; a3 = ab[3*VD_+j];
    }
    float wcA = 0.f, wcB = 0.f;
    if (j < M_) {
        wsh[0][j] = cb[0*M_+j];
        wsh[1][j] = cb[1*M_+j];
        wcA = cb[2*M_+j];
        wcB = cb[3*M_+j];
    }
    __syncthreads();

    for (int s = 0; s < S_; s += 2) {
        // stage corr rows s+2,s+3 (regs loaded one iteration ago) into ring.
        // (s+2)&3,(s+3)&3 are disjoint from the s&3,(s+1)&3 buffers read below.
        if (j < M_ && s + 2 < S_) {
            wsh[(s+2)&3][j] = wcA;
            wsh[(s+3)&3][j] = wcB;
        }
        // issue prefetch loads for rows s+4,s+5 (consumed 2 iterations later)
        float e4=0,a4=0,e5=0,a5=0, wcC=0.f, wcD=0.f;
        if (act && s+4 < S_) { e4 = eb[(s+4)*VD_+j]; a4 = ab[(s+4)*VD_+j]; }
        if (act && s+5 < S_) { e5 = eb[(s+5)*VD_+j]; a5 = ab[(s+5)*VD_+j]; }
        if (j < M_ && s+4 < S_) wcC = cb[(s+4)*M_+j];
        if (j < M_ && s+5 < S_) wcD = cb[(s+5)*M_+j];

        // step s
        {
            const float* w = wsh[s & 3];
            float r = 0.f;
#pragma unroll
            for (int m = 0; m < M_; m += 2) {
                float2 wp = *(const float2*)&w[m];
                float t0 = fmaf(-e0, mem[m], a0);
                r = fmaf(wp.x, mem[m], r);
                mem[m] = fmaf(wp.x, t0, mem[m]);
                float t1 = fmaf(-e0, mem[m+1], a0);
                r = fmaf(wp.y, mem[m+1], r);
                mem[m+1] = fmaf(wp.y, t1, mem[m+1]);
            }
            if (act) rb[s * VD_ + j] = r;
        }
        // step s+1
        {
            const float* w = wsh[(s+1) & 3];
            float r = 0.f;
#pragma unroll
            for (int m = 0; m < M_; m += 2) {
                float2 wp = *(const float2*)&w[m];
                float t0 = fmaf(-e1, mem[m], a1);
                r = fmaf(wp.x, mem[m], r);
                mem[m] = fmaf(wp.x, t0, mem[m]);
                float t1 = fmaf(-e1, mem[m+1], a1);
                r = fmaf(wp.y, mem[m+1], r);
                mem[m+1] = fmaf(wp.y, t1, mem[m+1]);
            }
            if (act) rb[(s+1) * VD_ + j] = r;
        }
        __syncthreads();
        // rotate pipeline (static names only)
        e0 = e2; a0 = a2; e1 = e3; a1 = a3;
        e2 = e4; a2 = a4; e3 = e5; a3 = a5;
        wcA = wcC; wcB = wcD;
    }
}

// ---------------------------------------------------------------------------
// Kernel 4: summary GEMM + fused head (unchanged).
// ---------------------------------------------------------------------------
#define BT4 80
#define KA  250
__global__ __launch_bounds__(256) void k4_head(
    const int* __restrict__ q_data, const float* __restrict__ q_tab,
    const float* __restrict__ reads,
    const float* __restrict__ W_sum, const float* __restrict__ b_sum,
    const float* __restrict__ W_ab, const float* __restrict__ b_ab,
    const float* __restrict__ W_th, const float* __restrict__ b_th,
    const float* __restrict__ W_disc, const float* __restrict__ b_disc,
    float* __restrict__ out)
{
    __shared__ __align__(16) float sAt[BK][84];
    __shared__ __align__(16) float sW[BK][52];
    __shared__ __align__(16) float sSum[BT4][52];
    __shared__ int sQ[BT4];

    const int tid  = threadIdx.x;
    const int tok0 = blockIdx.x * BT4;

    const int ty = tid / 25;
    const int tx = tid % 25;
    const bool act = (tid < 250);
    const int t0 = ty * 8;

    if (tid < BT4) sQ[tid] = q_data[tok0 + tid];

    float acc[8][2];
#pragma unroll
    for (int i = 0; i < 8; ++i) { acc[i][0] = 0.f; acc[i][1] = 0.f; }

    for (int kt = 0; kt < KA; kt += BK) {
        __syncthreads();
        for (int i = tid; i < BT4 * BK; i += 256) {
            int t = i / BK, kk = i % BK;
            float v;
            if (kt < VD_) v = reads[(size_t)(tok0 + t) * VD_ + kt + kk];
            else          v = q_tab[(size_t)sQ[t] * KD_ + (kt - VD_) + kk];
            sAt[kk][t] = v;
        }
        for (int i = tid; i < BK * FD_; i += 256) {
            int kk = i / FD_, col = i % FD_;
            sW[kk][col] = W_sum[(size_t)(kt + kk) * FD_ + col];
        }
        __syncthreads();

        if (act) {
#pragma unroll 5
            for (int kk = 0; kk < BK; ++kk) {
                float2 w = *(const float2*)&sW[kk][2 * tx];
                float4 a0 = *(const float4*)&sAt[kk][t0];
                float4 a1 = *(const float4*)&sAt[kk][t0 + 4];
                float av[8] = {a0.x, a0.y, a0.z, a0.w, a1.x, a1.y, a1.z, a1.w};
#pragma unroll
                for (int i = 0; i < 8; ++i) {
                    acc[i][0] += av[i] * w.x;
                    acc[i][1] += av[i] * w.y;
                }
            }
        }
    }

    if (act) {
        const float b0 = b_sum[2 * tx], b1 = b_sum[2 * tx + 1];
#pragma unroll
        for (int i = 0; i < 8; ++i) {
            sSum[t0 + i][2 * tx]     = tanhf(acc[i][0] + b0);
            sSum[t0 + i][2 * tx + 1] = tanhf(acc[i][1] + b1);
        }
    }
    __syncthreads();

    const int wv   = tid >> 6;
    const int lane = tid & 63;
    for (int lt = wv * 20; lt < wv * 20 + 20; ++lt) {
        const int tok = tok0 + lt;
        const float s  = (lane < FD_) ? sSum[lt][lane] : 0.0f;
        const int  qi  = sQ[lt];
        const float qv = (lane < KD_) ? q_tab[(size_t)qi * KD_ + lane] : 0.0f;

        float v_ab = (lane < FD_) ? s * W_ab[lane] : 0.0f;
        float v_d  = ((lane < FD_) ? s * W_disc[lane] : 0.0f)
                   + ((lane < KD_) ? qv * W_disc[FD_ + lane] : 0.0f);
        float v_t0 = (lane < KD_) ? qv * W_th[lane * 3 + 0] : 0.0f;
        float v_t1 = (lane < KD_) ? qv * W_th[lane * 3 + 1] : 0.0f;
        float v_t2 = (lane < KD_) ? qv * W_th[lane * 3 + 2] : 0.0f;

#pragma unroll
        for (int off = 32; off; off >>= 1) {
            v_ab += __shfl_xor(v_ab, off);
            v_d  += __shfl_xor(v_d,  off);
            v_t0 += __shfl_xor(v_t0, off);
            v_t1 += __shfl_xor(v_t1, off);
            v_t2 += __shfl_xor(v_t2, off);
        }

        if (lane == 0) {
            float theta = 3.0f * (v_ab + b_ab[0]);
            float xd = v_d + b_disc[0];
            float alpha = fmaxf(xd, 0.0f) + log1pf(expf(-fabsf(xd)));
            float beta0 = tanhf(v_t0 + b_th[0]);
            float beta1 = tanhf(v_t1 + b_th[1]);
            float beta2 = tanhf(v_t2 + b_th[2]);
            float c1 = alpha * (theta - beta0);
            float c2 = c1 + alpha * (theta - beta1);
            float c3 = c2 + alpha * (theta - beta2);
            float mx = fmaxf(fmaxf(0.0f, c1), fmaxf(c2, c3));
            float e0 = expf(0.0f - mx), e1 = expf(c1 - mx),
                  e2 = expf(c2 - mx), e3 = expf(c3 - mx);
            float s4 = e0 + e1 + e2 + e3;
            float4 o = make_float4(e0 / s4, e1 / s4, e2 / s4, e3 / s4);
            *(float4*)&out[(size_t)tok * 4] = o;
        }
    }
}

// ---------------------------------------------------------------------------
extern "C" void kernel_launch(void* const* d_in, const int* in_sizes, int n_in,
                              void* d_out, int out_size, void* d_ws, size_t ws_size,
                              hipStream_t stream) {
    const int*   q_data   = (const int*)  d_in[0];
    const int*   r_data   = (const int*)  d_in[1];
    const float* q_tab    = (const float*)d_in[2];
    const float* key_mem  = (const float*)d_in[3];
    const float* init_mem = (const float*)d_in[4];
    const float* W_qk     = (const float*)d_in[5];
    const float* b_qk     = (const float*)d_in[6];
    const float* W_v3     = (const float*)d_in[7];
    const float* b_v      = (const float*)d_in[8];
    const float* W_e      = (const float*)d_in[9];
    const float* b_e      = (const float*)d_in[10];
    const float* W_a      = (const float*)d_in[11];
    const float* b_a      = (const float*)d_in[12];
    const float* W_sum    = (const float*)d_in[13];
    const float* b_sum    = (const float*)d_in[14];
    const float* W_ab     = (const float*)d_in[15];
    const float* b_ab     = (const float*)d_in[16];
    const float* W_th     = (const float*)d_in[17];
    const float* b_th     = (const float*)d_in[18];
    const float* W_disc   = (const float*)d_in[19];
    const float* b_disc   = (const float*)d_in[20];

    float* ws    = (float*)d_ws;
    float* V     = ws;                       // T*VD
    float* reads = ws;                       // aliases V (V dead after k2)
    float* corr  = ws + (size_t)T_ * VD_;    // T*M
    float* erase = corr + (size_t)T_ * M_;   // T*VD
    float* add   = erase + (size_t)T_ * VD_; // T*VD

    k1_embed<<<T_ / 4, 256, 0, stream>>>(q_data, r_data, q_tab, key_mem,
                                         W_qk, b_qk, W_v3, b_v, V, corr);
    k2_gemm<<<T_ / BT2, 256, 0, stream>>>(V, W_e, b_e, W_a, b_a, erase, add);
    k3_scan<<<B_, 256, 0, stream>>>(init_mem, corr, erase, add, reads);
    k4_head<<<T_ / BT4, 256, 0, stream>>>(q_data, q_tab, reads,
                                          W_sum, b_sum, W_ab, b_ab,
                                          W_th, b_th, W_disc, b_disc,
                                          (float*)d_out);
}

// Round 6
// 427.248 us; speedup vs baseline: 1.8028x; 1.0252x over previous
//
#include <hip/hip_runtime.h>
#include <math.h>

#define B_   256
#define S_   200
#define NQ_  400
#define K_   4
#define M_   50
#define KD_  50
#define VD_  200
#define FD_  50
#define T_   (B_*S_)   // 51200 tokens

// ---------------------------------------------------------------------------
// Kernel 1: per-token embeddings + correlation softmax. One wave per token.
// ---------------------------------------------------------------------------
__global__ __launch_bounds__(256) void k1_embed(
    const int* __restrict__ q_data, const int* __restrict__ r_data,
    const float* __restrict__ q_tab, const float* __restrict__ key_mem,
    const float* __restrict__ W_qk, const float* __restrict__ b_qk,
    const float* __restrict__ W_v3, const float* __restrict__ b_v,
    float* __restrict__ V, float* __restrict__ corr)
{
    const int wave = threadIdx.x >> 6;
    const int lane = threadIdx.x & 63;
    const int tok  = blockIdx.x * 4 + wave;

    const int q = q_data[tok];
    const int r = r_data[tok];
    const float qmask = (q > 0) ? 1.0f : 0.0f;
    int idx = q - 1;
    if (idx < 0) idx = 0;
    if (idx > NQ_ - 1) idx = NQ_ - 1;

    float wc[K_];
#pragma unroll
    for (int k = 0; k < K_; ++k) {
        float dist = fabsf((float)k - (float)r) / (float)(K_ - 1);
        float w = 1.0f - dist;
        wc[k] = (w > 0.0f) ? w : 0.0f;
    }

    for (int j = lane; j < VD_; j += 64) {
        float s = 0.0f;
#pragma unroll
        for (int k = 0; k < K_; ++k)
            s += wc[k] * W_v3[((size_t)k * NQ_ + idx) * VD_ + j];
        V[(size_t)tok * VD_ + j] = b_v[j] + qmask * s;
    }

    __shared__ float sqk[4][KD_];
    const float* qe = q_tab + (size_t)q * KD_;
    if (lane < KD_) {
        float acc = b_qk[lane];
#pragma unroll 10
        for (int k = 0; k < KD_; ++k)
            acc += qe[k] * W_qk[k * KD_ + lane];
        sqk[wave][lane] = tanhf(acc);
    }
    __syncthreads();

    float c = -INFINITY;
    if (lane < M_) {
        float acc = 0.0f;
#pragma unroll 10
        for (int k = 0; k < KD_; ++k)
            acc += sqk[wave][k] * key_mem[lane * KD_ + k];
        c = acc;
    }
    float mx = c;
#pragma unroll
    for (int off = 32; off; off >>= 1) mx = fmaxf(mx, __shfl_xor(mx, off));
    float e = (lane < M_) ? expf(c - mx) : 0.0f;
    float sm = e;
#pragma unroll
    for (int off = 32; off; off >>= 1) sm += __shfl_xor(sm, off);
    if (lane < M_) corr[(size_t)tok * M_ + lane] = e / sm;
}

// ---------------------------------------------------------------------------
// Kernel 2 v3: register-blocked dual GEMM with software-pipelined staging.
// BK=10 (LDS 17.6KB -> occupancy VGPR-capped at ~50%), next tile's global
// loads issued into registers BEFORE compute (latency hides under 1280cy of
// FMA issue), ds_write after the post-compute barrier (T14 issue-early /
// write-late). Thread mapping unchanged: 8 tokens x 4 cols x 2 mats = 64 acc.
// ---------------------------------------------------------------------------
#define BT2 40
#define BKT 10
#define NTILES (VD_ / BKT)   // 20
__global__ __launch_bounds__(256) void k2_gemm(
    const float* __restrict__ V,
    const float* __restrict__ W_e, const float* __restrict__ b_e,
    const float* __restrict__ W_a, const float* __restrict__ b_a,
    float* __restrict__ erase, float* __restrict__ add)
{
    __shared__ float sWe[BKT][VD_];   // 8 KB
    __shared__ float sWa[BKT][VD_];   // 8 KB
    __shared__ float sVt[BKT][BT2];   // 1.6 KB

    const int tid = threadIdx.x;
    const int ty  = tid / 50;
    const int tx  = tid % 50;
    const bool act = (tid < 250);
    const int tok0 = blockIdx.x * BT2;
    const int c  = tx * 4;
    const int t0 = ty * 8;

    // staging slot assignments (fixed per thread):
    // W: 500 float4 per matrix per tile; thread tid<250 handles slots tid, tid+250
    const int ws0 = tid, ws1 = tid + 250;
    const int wr0 = ws0 / 50, wc0 = (ws0 % 50) * 4;
    const int wr1 = ws1 / 50, wc1 = (ws1 % 50) * 4;
    // V: 400 scalars per tile; thread tid<200 handles slots tid, tid+200
    const int vs0 = tid, vs1 = tid + 200;
    const int vk0 = vs0 / BT2, vt0 = vs0 % BT2;
    const int vk1 = vs1 / BT2, vt1 = vs1 % BT2;

    float accE[8][4], accA[8][4];
#pragma unroll
    for (int i = 0; i < 8; ++i)
#pragma unroll
        for (int l = 0; l < 4; ++l) { accE[i][l] = 0.f; accA[i][l] = 0.f; }

    // ---- stage tile 0 ----
    float4 rWe0, rWe1, rWa0, rWa1;
    float  rV0 = 0.f, rV1 = 0.f;
    if (act) {
        rWe0 = *(const float4*)&W_e[wr0 * VD_ + wc0];
        rWe1 = *(const float4*)&W_e[wr1 * VD_ + wc1];
        rWa0 = *(const float4*)&W_a[wr0 * VD_ + wc0];
        rWa1 = *(const float4*)&W_a[wr1 * VD_ + wc1];
    }
    if (tid < 200) {
        rV0 = V[(size_t)(tok0 + vt0) * VD_ + vk0];
        rV1 = V[(size_t)(tok0 + vt1) * VD_ + vk1];
    }
    if (act) {
        *(float4*)&sWe[wr0][wc0] = rWe0;
        *(float4*)&sWe[wr1][wc1] = rWe1;
        *(float4*)&sWa[wr0][wc0] = rWa0;
        *(float4*)&sWa[wr1][wc1] = rWa1;
    }
    if (tid < 200) {
        sVt[vk0][vt0] = rV0;
        sVt[vk1][vt1] = rV1;
    }
    __syncthreads();

    for (int t = 0; t < NTILES; ++t) {
        // issue next tile's global loads (consumed after the compute phase)
        const int ktn = (t + 1) * BKT;
        if (t + 1 < NTILES) {
            if (act) {
                rWe0 = *(const float4*)&W_e[(ktn + wr0) * VD_ + wc0];
                rWe1 = *(const float4*)&W_e[(ktn + wr1) * VD_ + wc1];
                rWa0 = *(const float4*)&W_a[(ktn + wr0) * VD_ + wc0];
                rWa1 = *(const float4*)&W_a[(ktn + wr1) * VD_ + wc1];
            }
            if (tid < 200) {
                rV0 = V[(size_t)(tok0 + vt0) * VD_ + ktn + vk0];
                rV1 = V[(size_t)(tok0 + vt1) * VD_ + ktn + vk1];
            }
        }

        // compute tile t
        if (act) {
#pragma unroll
            for (int kk = 0; kk < BKT; ++kk) {
                float4 we = *(const float4*)&sWe[kk][c];
                float4 wa = *(const float4*)&sWa[kk][c];
                float4 v0 = *(const float4*)&sVt[kk][t0];
                float4 v1 = *(const float4*)&sVt[kk][t0 + 4];
                float vv[8] = {v0.x, v0.y, v0.z, v0.w, v1.x, v1.y, v1.z, v1.w};
#pragma unroll
                for (int i = 0; i < 8; ++i) {
                    accE[i][0] = fmaf(vv[i], we.x, accE[i][0]);
                    accE[i][1] = fmaf(vv[i], we.y, accE[i][1]);
                    accE[i][2] = fmaf(vv[i], we.z, accE[i][2]);
                    accE[i][3] = fmaf(vv[i], we.w, accE[i][3]);
                    accA[i][0] = fmaf(vv[i], wa.x, accA[i][0]);
                    accA[i][1] = fmaf(vv[i], wa.y, accA[i][1]);
                    accA[i][2] = fmaf(vv[i], wa.z, accA[i][2]);
                    accA[i][3] = fmaf(vv[i], wa.w, accA[i][3]);
                }
            }
        }
        __syncthreads();   // all waves done reading LDS tile t

        if (t + 1 < NTILES) {
            if (act) {
                *(float4*)&sWe[wr0][wc0] = rWe0;
                *(float4*)&sWe[wr1][wc1] = rWe1;
                *(float4*)&sWa[wr0][wc0] = rWa0;
                *(float4*)&sWa[wr1][wc1] = rWa1;
            }
            if (tid < 200) {
                sVt[vk0][vt0] = rV0;
                sVt[vk1][vt1] = rV1;
            }
            __syncthreads();   // tile t+1 visible
        }
    }

    if (act) {
        const float4 be = *(const float4*)&b_e[c];
        const float4 ba = *(const float4*)&b_a[c];
#pragma unroll
        for (int i = 0; i < 8; ++i) {
            const size_t tok = tok0 + t0 + i;
            float4 eo, ao;
            eo.x = 1.0f / (1.0f + expf(-(accE[i][0] + be.x)));
            eo.y = 1.0f / (1.0f + expf(-(accE[i][1] + be.y)));
            eo.z = 1.0f / (1.0f + expf(-(accE[i][2] + be.z)));
            eo.w = 1.0f / (1.0f + expf(-(accE[i][3] + be.w)));
            ao.x = tanhf(accA[i][0] + ba.x);
            ao.y = tanhf(accA[i][1] + ba.y);
            ao.z = tanhf(accA[i][2] + ba.z);
            ao.w = tanhf(accA[i][3] + ba.w);
            *(float4*)&erase[tok * VD_ + c] = eo;
            *(float4*)&add[tok * VD_ + c]   = ao;
        }
    }
}

// ---------------------------------------------------------------------------
// Kernel 3: scan with 4-deep register pipeline (unchanged from round 4).
// ---------------------------------------------------------------------------
__global__ __launch_bounds__(256) void k3_scan(
    const float* __restrict__ init_mem,
    const float* __restrict__ corr, const float* __restrict__ erase,
    const float* __restrict__ add, float* __restrict__ reads)
{
    const int b = blockIdx.x;
    const int j = threadIdx.x;
    const bool act = (j < VD_);

    float mem[M_];
    if (act) {
#pragma unroll
        for (int m = 0; m < M_; ++m) mem[m] = init_mem[m * VD_ + j];
    }

    __shared__ float wsh[4][M_];
    const float* cb = corr  + (size_t)b * S_ * M_;
    const float* eb = erase + (size_t)b * S_ * VD_;
    const float* ab = add   + (size_t)b * S_ * VD_;
    float* rb       = reads + (size_t)b * S_ * VD_;

    float e0=0,a0=0,e1=0,a1=0,e2=0,a2=0,e3=0,a3=0;
    if (act) {
        e0 = eb[0*VD_+j]; a0 = ab[0*VD_+j];
        e1 = eb[1*VD_+j]; a1 = ab[1*VD_+j];
        e2 = eb[2*VD_+j]; a2 = ab[2*VD_+j];
        e3 = eb[3*VD_+j]; a3 = ab[3*VD_+j];
    }
    float wcA = 0.f, wcB = 0.f;
    if (j < M_) {
        wsh[0][j] = cb[0*M_+j];
        wsh[1][j] = cb[1*M_+j];
        wcA = cb[2*M_+j];
        wcB = cb[3*M_+j];
    }
    __syncthreads();

    for (int s = 0; s < S_; s += 2) {
        if (j < M_ && s + 2 < S_) {
            wsh[(s+2)&3][j] = wcA;
            wsh[(s+3)&3][j] = wcB;
        }
        float e4=0,a4=0,e5=0,a5=0, wcC=0.f, wcD=0.f;
        if (act && s+4 < S_) { e4 = eb[(s+4)*VD_+j]; a4 = ab[(s+4)*VD_+j]; }
        if (act && s+5 < S_) { e5 = eb[(s+5)*VD_+j]; a5 = ab[(s+5)*VD_+j]; }
        if (j < M_ && s+4 < S_) wcC = cb[(s+4)*M_+j];
        if (j < M_ && s+5 < S_) wcD = cb[(s+5)*M_+j];

        {
            const float* w = wsh[s & 3];
            float r = 0.f;
#pragma unroll
            for (int m = 0; m < M_; m += 2) {
                float2 wp = *(const float2*)&w[m];
                float t0 = fmaf(-e0, mem[m], a0);
                r = fmaf(wp.x, mem[m], r);
                mem[m] = fmaf(wp.x, t0, mem[m]);
                float t1 = fmaf(-e0, mem[m+1], a0);
                r = fmaf(wp.y, mem[m+1], r);
                mem[m+1] = fmaf(wp.y, t1, mem[m+1]);
            }
            if (act) rb[s * VD_ + j] = r;
        }
        {
            const float* w = wsh[(s+1) & 3];
            float r = 0.f;
#pragma unroll
            for (int m = 0; m < M_; m += 2) {
                float2 wp = *(const float2*)&w[m];
                float t0 = fmaf(-e1, mem[m], a1);
                r = fmaf(wp.x, mem[m], r);
                mem[m] = fmaf(wp.x, t0, mem[m]);
                float t1 = fmaf(-e1, mem[m+1], a1);
                r = fmaf(wp.y, mem[m+1], r);
                mem[m+1] = fmaf(wp.y, t1, mem[m+1]);
            }
            if (act) rb[(s+1) * VD_ + j] = r;
        }
        __syncthreads();
        e0 = e2; a0 = a2; e1 = e3; a1 = a3;
        e2 = e4; a2 = a4; e3 = e5; a3 = a5;
        wcA = wcC; wcB = wcD;
    }
}

// ---------------------------------------------------------------------------
// Kernel 4: summary GEMM + fused head (unchanged).
// ---------------------------------------------------------------------------
#define BT4 80
#define KA  250
#define BK4 25
__global__ __launch_bounds__(256) void k4_head(
    const int* __restrict__ q_data, const float* __restrict__ q_tab,
    const float* __restrict__ reads,
    const float* __restrict__ W_sum, const float* __restrict__ b_sum,
    const float* __restrict__ W_ab, const float* __restrict__ b_ab,
    const float* __restrict__ W_th, const float* __restrict__ b_th,
    const float* __restrict__ W_disc, const float* __restrict__ b_disc,
    float* __restrict__ out)
{
    __shared__ __align__(16) float sAt[BK4][84];
    __shared__ __align__(16) float sW[BK4][52];
    __shared__ __align__(16) float sSum[BT4][52];
    __shared__ int sQ[BT4];

    const int tid  = threadIdx.x;
    const int tok0 = blockIdx.x * BT4;

    const int ty = tid / 25;
    const int tx = tid % 25;
    const bool act = (tid < 250);
    const int t0 = ty * 8;

    if (tid < BT4) sQ[tid] = q_data[tok0 + tid];

    float acc[8][2];
#pragma unroll
    for (int i = 0; i < 8; ++i) { acc[i][0] = 0.f; acc[i][1] = 0.f; }

    for (int kt = 0; kt < KA; kt += BK4) {
        __syncthreads();
        for (int i = tid; i < BT4 * BK4; i += 256) {
            int t = i / BK4, kk = i % BK4;
            float v;
            if (kt < VD_) v = reads[(size_t)(tok0 + t) * VD_ + kt + kk];
            else          v = q_tab[(size_t)sQ[t] * KD_ + (kt - VD_) + kk];
            sAt[kk][t] = v;
        }
        for (int i = tid; i < BK4 * FD_; i += 256) {
            int kk = i / FD_, col = i % FD_;
            sW[kk][col] = W_sum[(size_t)(kt + kk) * FD_ + col];
        }
        __syncthreads();

        if (act) {
#pragma unroll 5
            for (int kk = 0; kk < BK4; ++kk) {
                float2 w = *(const float2*)&sW[kk][2 * tx];
                float4 a0 = *(const float4*)&sAt[kk][t0];
                float4 a1 = *(const float4*)&sAt[kk][t0 + 4];
                float av[8] = {a0.x, a0.y, a0.z, a0.w, a1.x, a1.y, a1.z, a1.w};
#pragma unroll
                for (int i = 0; i < 8; ++i) {
                    acc[i][0] += av[i] * w.x;
                    acc[i][1] += av[i] * w.y;
                }
            }
        }
    }

    if (act) {
        const float b0 = b_sum[2 * tx], b1 = b_sum[2 * tx + 1];
#pragma unroll
        for (int i = 0; i < 8; ++i) {
            sSum[t0 + i][2 * tx]     = tanhf(acc[i][0] + b0);
            sSum[t0 + i][2 * tx + 1] = tanhf(acc[i][1] + b1);
        }
    }
    __syncthreads();

    const int wv   = tid >> 6;
    const int lane = tid & 63;
    for (int lt = wv * 20; lt < wv * 20 + 20; ++lt) {
        const int tok = tok0 + lt;
        const float s  = (lane < FD_) ? sSum[lt][lane] : 0.0f;
        const int  qi  = sQ[lt];
        const float qv = (lane < KD_) ? q_tab[(size_t)qi * KD_ + lane] : 0.0f;

        float v_ab = (lane < FD_) ? s * W_ab[lane] : 0.0f;
        float v_d  = ((lane < FD_) ? s * W_disc[lane] : 0.0f)
                   + ((lane < KD_) ? qv * W_disc[FD_ + lane] : 0.0f);
        float v_t0 = (lane < KD_) ? qv * W_th[lane * 3 + 0] : 0.0f;
        float v_t1 = (lane < KD_) ? qv * W_th[lane * 3 + 1] : 0.0f;
        float v_t2 = (lane < KD_) ? qv * W_th[lane * 3 + 2] : 0.0f;

#pragma unroll
        for (int off = 32; off; off >>= 1) {
            v_ab += __shfl_xor(v_ab, off);
            v_d  += __shfl_xor(v_d,  off);
            v_t0 += __shfl_xor(v_t0, off);
            v_t1 += __shfl_xor(v_t1, off);
            v_t2 += __shfl_xor(v_t2, off);
        }

        if (lane == 0) {
            float theta = 3.0f * (v_ab + b_ab[0]);
            float xd = v_d + b_disc[0];
            float alpha = fmaxf(xd, 0.0f) + log1pf(expf(-fabsf(xd)));
            float beta0 = tanhf(v_t0 + b_th[0]);
            float beta1 = tanhf(v_t1 + b_th[1]);
            float beta2 = tanhf(v_t2 + b_th[2]);
            float c1 = alpha * (theta - beta0);
            float c2 = c1 + alpha * (theta - beta1);
            float c3 = c2 + alpha * (theta - beta2);
            float mx = fmaxf(fmaxf(0.0f, c1), fmaxf(c2, c3));
            float e0 = expf(0.0f - mx), e1 = expf(c1 - mx),
                  e2 = expf(c2 - mx), e3 = expf(c3 - mx);
            float s4 = e0 + e1 + e2 + e3;
            float4 o = make_float4(e0 / s4, e1 / s4, e2 / s4, e3 / s4);
            *(float4*)&out[(size_t)tok * 4] = o;
        }
    }
}

// ---------------------------------------------------------------------------
extern "C" void kernel_launch(void* const* d_in, const int* in_sizes, int n_in,
                              void* d_out, int out_size, void* d_ws, size_t ws_size,
                              hipStream_t stream) {
    const int*   q_data   = (const int*)  d_in[0];
    const int*   r_data   = (const int*)  d_in[1];
    const float* q_tab    = (const float*)d_in[2];
    const float* key_mem  = (const float*)d_in[3];
    const float* init_mem = (const float*)d_in[4];
    const float* W_qk     = (const float*)d_in[5];
    const float* b_qk     = (const float*)d_in[6];
    const float* W_v3     = (const float*)d_in[7];
    const float* b_v      = (const float*)d_in[8];
    const float* W_e      = (const float*)d_in[9];
    const float* b_e      = (const float*)d_in[10];
    const float* W_a      = (const float*)d_in[11];
    const float* b_a      = (const float*)d_in[12];
    const float* W_sum    = (const float*)d_in[13];
    const float* b_sum    = (const float*)d_in[14];
    const float* W_ab     = (const float*)d_in[15];
    const float* b_ab     = (const float*)d_in[16];
    const float* W_th     = (const float*)d_in[17];
    const float* b_th     = (const float*)d_in[18];
    const float* W_disc   = (const float*)d_in[19];
    const float* b_disc   = (const float*)d_in[20];

    float* ws    = (float*)d_ws;
    float* V     = ws;                       // T*VD
    float* reads = ws;                       // aliases V (V dead after k2)
    float* corr  = ws + (size_t)T_ * VD_;    // T*M
    float* erase = corr + (size_t)T_ * M_;   // T*VD
    float* add   = erase + (size_t)T_ * VD_; // T*VD

    k1_embed<<<T_ / 4, 256, 0, stream>>>(q_data, r_data, q_tab, key_mem,
                                         W_qk, b_qk, W_v3, b_v, V, corr);
    k2_gemm<<<T_ / BT2, 256, 0, stream>>>(V, W_e, b_e, W_a, b_a, erase, add);
    k3_scan<<<B_, 256, 0, stream>>>(init_mem, corr, erase, add, reads);
    k4_head<<<T_ / BT4, 256, 0, stream>>>(q_data, q_tab, reads,
                                          W_sum, b_sum, W_ab, b_ab,
                                          W_th, b_th, W_disc, b_disc,
                                          (float*)d_out);
}